// Round 1
// baseline (509.608 us; speedup 1.0000x reference)
//
#include <hip/hip_runtime.h>
#include <math.h>

// Problem constants
#define TTOK   16384      // B*S tokens
#define HDIM   4096
#define ENUM   64         // experts
#define KTOP   6
#define GNUM   8
#define TGK    3
#define BBATCH 4
#define SSEQ   4096
#define ALPHAC 0.001f

// GEMM tiling
#define KSPLIT 2
#define BM     64
#define BK     64
#define KH     (HDIM / KSPLIT)   // 2048 per k-half
#define NIT    (KH / BK)         // 32 iters
#define XSTR   68                // Xs row stride (floats): 272B, 16B-aligned, 2-way banks
#define WSTR   68                // Ws row stride (floats)

// ---------------------------------------------------------------------------
// Kernel 1: gate GEMM. logits_partial[half][T][64] = X[:, half] @ W[:, half]^T
// ---------------------------------------------------------------------------
__global__ __launch_bounds__(256, 2)
void gate_gemm(const float* __restrict__ X, const float* __restrict__ W,
               float* __restrict__ lp) {
    __shared__ __align__(16) float Xs[BM * XSTR];
    __shared__ __align__(16) float Ws[BK * WSTR];   // [k][expert] layout

    const int tid  = threadIdx.x;
    const int bid  = blockIdx.x;
    const int tile = bid & 255;     // token tile 0..255
    const int half = bid >> 8;      // k-half 0..1
    const int tok0 = tile * BM;
    const int k0   = half * KH;

    const int tx = tid & 15;        // expert col group: experts 4*tx..4*tx+3
    const int ty = tid >> 4;        // token row group: tokens 4*ty..4*ty+3

    const int c4  = tid & 15;       // float4 column for staging
    const int rw  = tid >> 4;       // base row for staging passes

    float acc[4][4];
#pragma unroll
    for (int r = 0; r < 4; ++r)
#pragma unroll
        for (int c = 0; c < 4; ++c) acc[r][c] = 0.f;

    float4 xst[4], wst[4];

    // prefetch iter 0
#pragma unroll
    for (int p = 0; p < 4; ++p) {
        const int row = p * 16 + rw;    // token row / expert row, 0..63
        xst[p] = *(const float4*)(X + (size_t)(tok0 + row) * HDIM + k0 + c4 * 4);
        wst[p] = *(const float4*)(W + (size_t)row * HDIM + k0 + c4 * 4);
    }

    for (int it = 0; it < NIT; ++it) {
        __syncthreads();
        // commit staged regs to LDS
#pragma unroll
        for (int p = 0; p < 4; ++p) {
            const int row = p * 16 + rw;
            *(float4*)(Xs + row * XSTR + c4 * 4) = xst[p];
            // W transposed into [k][expert]
            Ws[(c4 * 4 + 0) * WSTR + row] = wst[p].x;
            Ws[(c4 * 4 + 1) * WSTR + row] = wst[p].y;
            Ws[(c4 * 4 + 2) * WSTR + row] = wst[p].z;
            Ws[(c4 * 4 + 3) * WSTR + row] = wst[p].w;
        }
        __syncthreads();

        if (it + 1 < NIT) {
            const int kk = k0 + (it + 1) * BK;
#pragma unroll
            for (int p = 0; p < 4; ++p) {
                const int row = p * 16 + rw;
                xst[p] = *(const float4*)(X + (size_t)(tok0 + row) * HDIM + kk + c4 * 4);
                wst[p] = *(const float4*)(W + (size_t)row * HDIM + kk + c4 * 4);
            }
        }

        // inner compute: 16 k-steps x (8 ds_read_b128 + 64 v_fma_f32)
#pragma unroll
        for (int ks = 0; ks < BK; ks += 4) {
            float4 xv[4], wv[4];
#pragma unroll
            for (int r = 0; r < 4; ++r)
                xv[r] = *(const float4*)(Xs + (4 * ty + r) * XSTR + ks);
#pragma unroll
            for (int j = 0; j < 4; ++j)
                wv[j] = *(const float4*)(Ws + (ks + j) * WSTR + 4 * tx);
#pragma unroll
            for (int r = 0; r < 4; ++r) {
                const float* xf = (const float*)&xv[r];
#pragma unroll
                for (int j = 0; j < 4; ++j) {
                    const float* wf = (const float*)&wv[j];
#pragma unroll
                    for (int c = 0; c < 4; ++c)
                        acc[r][c] = fmaf(xf[j], wf[c], acc[r][c]);
                }
            }
        }
    }

    // write partial logits
#pragma unroll
    for (int r = 0; r < 4; ++r) {
        float4 v = make_float4(acc[r][0], acc[r][1], acc[r][2], acc[r][3]);
        *(float4*)(lp + (size_t)half * TTOK * ENUM
                      + (size_t)(tok0 + 4 * ty + r) * ENUM + 4 * tx) = v;
    }
}

// ---------------------------------------------------------------------------
// Kernel 2: softmax + group-limited top-k + weights, per-token (one wave/token)
// ---------------------------------------------------------------------------
__global__ __launch_bounds__(256)
void router_topk(const float* __restrict__ lp,
                 float* __restrict__ out_idx, float* __restrict__ out_w,
                 float* __restrict__ ssum_g, int* __restrict__ cnt_g) {
    __shared__ float s_ssum[ENUM];
    __shared__ int   s_cnt[ENUM];
    const int tid = threadIdx.x;
    if (tid < ENUM) { s_ssum[tid] = 0.f; s_cnt[tid] = 0; }
    __syncthreads();

    const int lane = tid & 63;     // expert id
    const int wv   = tid >> 6;     // wave 0..3
    const int g    = lane >> 3;    // group id

    float ss_local = 0.f;
    int   cnt_local = 0;

    const int tok_base = blockIdx.x * 64 + wv * 16;

    for (int i = 0; i < 16; ++i) {
        const int t = tok_base + i;
        float logit = lp[(size_t)t * ENUM + lane]
                    + lp[(size_t)TTOK * ENUM + (size_t)t * ENUM + lane];

        // softmax over 64 experts
        float m = logit;
#pragma unroll
        for (int off = 32; off; off >>= 1) m = fmaxf(m, __shfl_xor(m, off));
        float ex = expf(logit - m);
        float sum = ex;
#pragma unroll
        for (int off = 32; off; off >>= 1) sum += __shfl_xor(sum, off);
        const float score = ex / sum;

        // group max (within aligned groups of 8 lanes)
        float gm = score;
#pragma unroll
        for (int off = 1; off < 8; off <<= 1) gm = fmaxf(gm, __shfl_xor(gm, off));

        // group rank: #groups strictly better, ties broken by lower group idx
        int rank = 0;
#pragma unroll
        for (int gg = 0; gg < GNUM; ++gg) {
            float gvo = __shfl(gm, gg * 8);
            rank += (gvo > gm) || (gvo == gm && gg < g);
        }
        const bool sel_group = (rank < TGK);
        const float ms = sel_group ? score : 0.0f;

        // top-6 via 6 wave argmax passes (strict > keeps lowest index on ties)
        int   taken = 0;
        float my_i = 0.f, my_w = 0.f;
        float wsum = 0.f;
#pragma unroll
        for (int j = 0; j < KTOP; ++j) {
            float v = taken ? -1.0f : ms;
            int   idx = lane;
#pragma unroll
            for (int off = 32; off; off >>= 1) {
                float vo = __shfl_xor(v, off);
                int   io = __shfl_xor(idx, off);
                if (vo > v || (vo == v && io < idx)) { v = vo; idx = io; }
            }
            wsum += v;
            if (lane == idx) taken = 1;
            if (lane == j) { my_i = (float)idx; my_w = v; }
        }
        const float inv = 1.0f / (wsum + 1e-20f);
        if (lane < KTOP) {
            out_idx[(size_t)t * KTOP + lane] = my_i;
            out_w[(size_t)t * KTOP + lane]   = my_w * inv;
        }

        ss_local += score;
        cnt_local += taken;
    }

    atomicAdd(&s_ssum[lane], ss_local);
    atomicAdd(&s_cnt[lane], cnt_local);
    __syncthreads();

    const int b = (blockIdx.x * 64) / SSEQ;   // 64 tokens never straddle a batch
    if (tid < ENUM) {
        atomicAdd(&ssum_g[b * ENUM + tid], s_ssum[tid]);
        atomicAdd(&cnt_g[b * ENUM + tid], s_cnt[tid]);
    }
}

// ---------------------------------------------------------------------------
// Kernel 3: aux loss reduction (1 block, 256 threads = 4 batches x 64 experts)
// ---------------------------------------------------------------------------
__global__ __launch_bounds__(256)
void aux_loss(const float* __restrict__ ssum_g, const int* __restrict__ cnt_g,
              float* __restrict__ out_aux) {
    const int tid = threadIdx.x;   // (b,e) pair
    // ce = count / (S*K/E);  mean_score = ssum / S
    float v = (float)cnt_g[tid] * (float)ENUM / ((float)SSEQ * (float)KTOP)
            * (ssum_g[tid] / (float)SSEQ);
#pragma unroll
    for (int off = 32; off; off >>= 1) v += __shfl_xor(v, off);
    __shared__ float red[4];
    if ((tid & 63) == 0) red[tid >> 6] = v;
    __syncthreads();
    if (tid == 0)
        out_aux[0] = (red[0] + red[1] + red[2] + red[3]) * (ALPHAC / (float)BBATCH);
}

// ---------------------------------------------------------------------------
extern "C" void kernel_launch(void* const* d_in, const int* in_sizes, int n_in,
                              void* d_out, int out_size, void* d_ws, size_t ws_size,
                              hipStream_t stream) {
    const float* X = (const float*)d_in[0];   // [4,4096,4096] fp32
    const float* W = (const float*)d_in[1];   // [64,4096] fp32

    float* out     = (float*)d_out;
    float* out_idx = out;                        // [T*6] indices (as float)
    float* out_w   = out + (size_t)TTOK * KTOP;  // [T*6] weights
    float* out_aux = out + (size_t)2 * TTOK * KTOP; // scalar

    float* lp     = (float*)d_ws;                        // [2][T][64] = 8 MiB
    float* ssum_g = lp + (size_t)KSPLIT * TTOK * ENUM;   // [4][64]
    int*   cnt_g  = (int*)(ssum_g + BBATCH * ENUM);      // [4][64]

    hipMemsetAsync(ssum_g, 0, BBATCH * ENUM * (sizeof(float) + sizeof(int)), stream);

    gate_gemm<<<256 * KSPLIT, 256, 0, stream>>>(X, W, lp);
    router_topk<<<TTOK / 64, 256, 0, stream>>>(lp, out_idx, out_w, ssum_g, cnt_g);
    aux_loss<<<1, 256, 0, stream>>>(ssum_g, cnt_g, out_aux);
}